// Round 1
// baseline (296.286 us; speedup 1.0000x reference)
//
#include <hip/hip_runtime.h>
#include <math.h>

#define NTOK 16384   // B*T = 4*4096
#define DDIM 4096
#define NEXP 64
#define TM   64      // tokens per block
#define KC   32      // K chunk staged in LDS
#define XS   36      // X tile row stride in floats (padded, 16B-aligned)
#define NTHR 512
#define NCHUNK (DDIM / KC)

__device__ __forceinline__ bool better(float va, int ia, float vb, int ib) {
  // strict total order matching jax.lax.top_k: larger value wins, ties -> lower index
  return (va > vb) || (va == vb && ia < ib);
}

__global__ __launch_bounds__(NTHR)
void topk_router_kernel(const float* __restrict__ x, const float* __restrict__ w,
                        float* __restrict__ out) {
  // LDS: X row-major [tok][k] (padded stride), W transposed k-major [k][expert]
  __shared__ float Xs[2][TM][XS];
  __shared__ float Wk[2][KC][NEXP];

  const int u = threadIdx.x;
  const int tokBase = blockIdx.x * TM;
  const int tx = u & 15;    // expert group: experts tx*4 .. tx*4+3
  const int ty = u >> 4;    // token pair: tokens ty*2, ty*2+1
  const int stok = u >> 3;  // staging row (0..63): token row for X, expert row for W
  const int skq  = u & 7;   // staging k-quad (0..7)

  double acc[2][4];
#pragma unroll
  for (int j = 0; j < 2; ++j)
#pragma unroll
    for (int i = 0; i < 4; ++i) acc[j][i] = 0.0;

  const float* xp = x + (size_t)(tokBase + stok) * DDIM + skq * 4;
  const float* wp = w + (size_t)stok * DDIM + skq * 4;

  // prologue: stage chunk 0
  float4 xr = *(const float4*)(xp);
  float4 wr = *(const float4*)(wp);
  *(float4*)&Xs[0][stok][skq * 4] = xr;
  Wk[0][skq * 4 + 0][stok] = wr.x;
  Wk[0][skq * 4 + 1][stok] = wr.y;
  Wk[0][skq * 4 + 2][stok] = wr.z;
  Wk[0][skq * 4 + 3][stok] = wr.w;
  __syncthreads();

  const int tok0 = ty * 2;
  const int e0 = tx * 4;

  for (int c = 0; c < NCHUNK; ++c) {
    const int cur = c & 1;
    if (c + 1 < NCHUNK) {  // issue next-chunk global loads early (hide under compute)
      xr = *(const float4*)(xp + (c + 1) * KC);
      wr = *(const float4*)(wp + (c + 1) * KC);
    }
#pragma unroll
    for (int k0 = 0; k0 < KC; k0 += 4) {
      float4 xv0 = *(const float4*)&Xs[cur][tok0][k0];
      float4 xv1 = *(const float4*)&Xs[cur][tok0 + 1][k0];
      float4 wv0 = *(const float4*)&Wk[cur][k0 + 0][e0];
      float4 wv1 = *(const float4*)&Wk[cur][k0 + 1][e0];
      float4 wv2 = *(const float4*)&Wk[cur][k0 + 2][e0];
      float4 wv3 = *(const float4*)&Wk[cur][k0 + 3][e0];
      const float* xa0 = (const float*)&xv0;
      const float* xa1 = (const float*)&xv1;
      const float* was[4] = {(const float*)&wv0, (const float*)&wv1,
                             (const float*)&wv2, (const float*)&wv3};
#pragma unroll
      for (int k = 0; k < 4; ++k) {
        const double x0d = (double)xa0[k];
        const double x1d = (double)xa1[k];
        const float* wa = was[k];
#pragma unroll
        for (int i = 0; i < 4; ++i) {
          const double wd = (double)wa[i];
          acc[0][i] = fma(x0d, wd, acc[0][i]);
          acc[1][i] = fma(x1d, wd, acc[1][i]);
        }
      }
    }
    if (c + 1 < NCHUNK) {
      const int nxt = cur ^ 1;
      *(float4*)&Xs[nxt][stok][skq * 4] = xr;
      Wk[nxt][skq * 4 + 0][stok] = wr.x;
      Wk[nxt][skq * 4 + 1][stok] = wr.y;
      Wk[nxt][skq * 4 + 2][stok] = wr.z;
      Wk[nxt][skq * 4 + 3][stok] = wr.w;
    }
    __syncthreads();
  }

  // output layout: [idx as float: 32768][weights: 32768][logits: 1048576]
  float* out_idx = out;
  float* out_wt  = out + NTOK * 2;
  float* out_lg  = out + NTOK * 4;

  float lv[2][4];
#pragma unroll
  for (int j = 0; j < 2; ++j) {
#pragma unroll
    for (int i = 0; i < 4; ++i) lv[j][i] = (float)acc[j][i];
    float4 o = make_float4(lv[j][0], lv[j][1], lv[j][2], lv[j][3]);
    *(float4*)&out_lg[(size_t)(tokBase + tok0 + j) * NEXP + e0] = o;
  }

#pragma unroll
  for (int j = 0; j < 2; ++j) {
    // in-thread top-2 of 4 (indices ascending, so strict compare keeps lowest index on tie)
    float v0 = lv[j][0]; int i0 = e0;
    float v1 = lv[j][1]; int i1 = e0 + 1;
    if (better(v1, i1, v0, i0)) {
      float tv = v0; v0 = v1; v1 = tv;
      int ti = i0; i0 = i1; i1 = ti;
    }
#pragma unroll
    for (int i = 2; i < 4; ++i) {
      float cv = lv[j][i]; int ic = e0 + i;
      if (better(cv, ic, v0, i0)) { v1 = v0; i1 = i0; v0 = cv; i0 = ic; }
      else if (better(cv, ic, v1, i1)) { v1 = cv; i1 = ic; }
    }
    // butterfly across the 16 lanes (tx 0..15) that share this token row
#pragma unroll
    for (int m = 1; m <= 8; m <<= 1) {
      float b0 = __shfl_xor(v0, m);
      int  jb0 = __shfl_xor(i0, m);
      float b1 = __shfl_xor(v1, m);
      int  jb1 = __shfl_xor(i1, m);
      if (better(b0, jb0, v0, i0)) {
        float nv1; int ni1;
        if (better(v0, i0, b1, jb1)) { nv1 = v0; ni1 = i0; }
        else                         { nv1 = b1; ni1 = jb1; }
        v0 = b0; i0 = jb0; v1 = nv1; i1 = ni1;
      } else if (better(b0, jb0, v1, i1)) {
        v1 = b0; i1 = jb0;
      }
    }
    if (tx == 0) {
      const int tok = tokBase + tok0 + j;
      // softmax over [v0, v1] with v0 = max (matches jax: exp(l - max) / sum)
      float ex = expf(v1 - v0);
      float denom = 1.0f + ex;
      out_idx[tok * 2 + 0] = (float)i0;
      out_idx[tok * 2 + 1] = (float)i1;
      out_wt[tok * 2 + 0] = 1.0f / denom;
      out_wt[tok * 2 + 1] = ex / denom;
    }
  }
}

extern "C" void kernel_launch(void* const* d_in, const int* in_sizes, int n_in,
                              void* d_out, int out_size, void* d_ws, size_t ws_size,
                              hipStream_t stream) {
  const float* x = (const float*)d_in[0];  // [4,4096,4096] f32
  const float* w = (const float*)d_in[1];  // [64,4096] f32
  float* out = (float*)d_out;              // 32768 idx + 32768 wt + 1048576 logits
  dim3 grid(NTOK / TM);   // 256 blocks = 1 per CU
  dim3 block(NTHR);       // 512 threads = 8 waves
  hipLaunchKernelGGL(topk_router_kernel, grid, block, 0, stream, x, w, out);
}

// Round 2
// 103.198 us; speedup vs baseline: 2.8710x; 2.8710x over previous
//
#include <hip/hip_runtime.h>
#include <math.h>

#define NTOK 16384
#define DDIM 4096
#define NEXP 64
#define TM   64
#define KC   32
#define NC   (DDIM / KC)   // 128 k-chunks
#define NTHR 512
#define TAU  2e-4f

typedef short bf16x8 __attribute__((ext_vector_type(8)));
typedef float f32x4  __attribute__((ext_vector_type(4)));

__device__ __forceinline__ unsigned short bf16_rne(float f) {
  unsigned u = __float_as_uint(f);
  u += 0x7fffu + ((u >> 16) & 1u);
  return (unsigned short)(u >> 16);
}

__device__ __forceinline__ void split4(float4 v, uint2& hi, uint2& lo) {
  unsigned h0 = bf16_rne(v.x), h1 = bf16_rne(v.y), h2 = bf16_rne(v.z), h3 = bf16_rne(v.w);
  float r0 = v.x - __uint_as_float(h0 << 16);
  float r1 = v.y - __uint_as_float(h1 << 16);
  float r2 = v.z - __uint_as_float(h2 << 16);
  float r3 = v.w - __uint_as_float(h3 << 16);
  unsigned l0 = bf16_rne(r0), l1 = bf16_rne(r1), l2 = bf16_rne(r2), l3 = bf16_rne(r3);
  hi = make_uint2(h0 | (h1 << 16), h2 | (h3 << 16));
  lo = make_uint2(l0 | (l1 << 16), l2 | (l3 << 16));
}

__device__ __forceinline__ bool better(float va, int ia, float vb, int ib) {
  return (va > vb) || (va == vb && ia < ib);
}
__device__ __forceinline__ bool betterd(double va, int ia, double vb, int ib) {
  return (va > vb) || (va == vb && ia < ib);
}

// compare-exchange keeping the "better" (max) in slot a
#define CE(va, ia, vb, ib) { if (better(vb, ib, va, ia)) { float _tv = va; va = vb; vb = _tv; int _ti = ia; ia = ib; ib = _ti; } }

__global__ __launch_bounds__(NTHR)
void topk_router_mfma(const float* __restrict__ x, const float* __restrict__ wgt,
                      float* __restrict__ out) {
  // stage buf layout (shorts): [0,2048) Xhi (4 tiles x 512), [2048,4096) Xlo,
  //                            [4096,6144) Whi, [6144,8192) Wlo
  // tile = 16 rows x 32 k, fragment-linear: slot s=(row&15)+16*(k>>3) at s*16B, byte (k&7)*2
  __shared__ __align__(16) short stage[2][8192];
  __shared__ __align__(16) float Lg[64][68];
  __shared__ int flagCount;
  __shared__ int flagTok[64];
  __shared__ unsigned flagIdx[64];

  const int u = threadIdx.x;
  const int l = u & 63;
  const int wid = u >> 6;        // wave 0..7
  const int wr = wid >> 1;       // M-quarter 0..3 (16 tokens)
  const int wc = wid & 1;        // N-half 0..1 (32 experts)
  const int tokBase = blockIdx.x * TM;

  // staging assignment: row = u>>3 (token for X / expert for W), k-quad = u&7
  const int stok = u >> 3;
  const int skq  = u & 7;
  const int soff = (stok >> 4) * 512 + ((stok & 15) + 16 * (skq >> 1)) * 8 + (skq & 1) * 4;

  const float* xgp = x   + (size_t)(tokBase + stok) * DDIM + skq * 4;
  const float* wgp = wgt + (size_t)stok * DDIM + skq * 4;

  // MFMA read offsets (shorts), loop-invariant
  const int aoff  = wr * 512 + l * 8;
  const int b0off = (wc * 2) * 512 + l * 8;
  const int b1off = b0off + 512;

  f32x4 acc0 = {0.f, 0.f, 0.f, 0.f};
  f32x4 acc1 = {0.f, 0.f, 0.f, 0.f};

  if (u == 0) flagCount = 0;

  float4 xA = *(const float4*)(xgp);
  float4 wA = *(const float4*)(wgp);
  float4 xB = *(const float4*)(xgp + KC);
  float4 wB = *(const float4*)(wgp + KC);

  {
    uint2 h, lo2;
    split4(xA, h, lo2);
    *(uint2*)(&stage[0][soff]) = h;
    *(uint2*)(&stage[0][2048 + soff]) = lo2;
    split4(wA, h, lo2);
    *(uint2*)(&stage[0][4096 + soff]) = h;
    *(uint2*)(&stage[0][6144 + soff]) = lo2;
  }
  __syncthreads();

#define COMPUTE(BUF)                                                              \
  {                                                                               \
    const short* bs = &stage[BUF][0];                                             \
    bf16x8 ahi = *(const bf16x8*)(bs + aoff);                                     \
    bf16x8 alo = *(const bf16x8*)(bs + 2048 + aoff);                              \
    bf16x8 b0h = *(const bf16x8*)(bs + 4096 + b0off);                             \
    bf16x8 b0l = *(const bf16x8*)(bs + 6144 + b0off);                             \
    bf16x8 b1h = *(const bf16x8*)(bs + 4096 + b1off);                             \
    bf16x8 b1l = *(const bf16x8*)(bs + 6144 + b1off);                             \
    acc0 = __builtin_amdgcn_mfma_f32_16x16x32_bf16(ahi, b0h, acc0, 0, 0, 0);      \
    acc1 = __builtin_amdgcn_mfma_f32_16x16x32_bf16(ahi, b1h, acc1, 0, 0, 0);      \
    acc0 = __builtin_amdgcn_mfma_f32_16x16x32_bf16(ahi, b0l, acc0, 0, 0, 0);      \
    acc1 = __builtin_amdgcn_mfma_f32_16x16x32_bf16(ahi, b1l, acc1, 0, 0, 0);      \
    acc0 = __builtin_amdgcn_mfma_f32_16x16x32_bf16(alo, b0h, acc0, 0, 0, 0);      \
    acc1 = __builtin_amdgcn_mfma_f32_16x16x32_bf16(alo, b1h, acc1, 0, 0, 0);      \
  }

#define STAGEW(BUF, XV, WV)                                                       \
  {                                                                               \
    uint2 h, lo2;                                                                 \
    split4(XV, h, lo2);                                                           \
    *(uint2*)(&stage[BUF][soff]) = h;                                             \
    *(uint2*)(&stage[BUF][2048 + soff]) = lo2;                                    \
    split4(WV, h, lo2);                                                           \
    *(uint2*)(&stage[BUF][4096 + soff]) = h;                                      \
    *(uint2*)(&stage[BUF][6144 + soff]) = lo2;                                    \
  }

  for (int c = 0; c < NC; c += 2) {
    if (c + 2 < NC) { xA = *(const float4*)(xgp + (c + 2) * KC); wA = *(const float4*)(wgp + (c + 2) * KC); }
    COMPUTE(0)
    STAGEW(1, xB, wB)          // chunk c+1 (always exists: NC even)
    __syncthreads();
    if (c + 3 < NC) { xB = *(const float4*)(xgp + (c + 3) * KC); wB = *(const float4*)(wgp + (c + 3) * KC); }
    COMPUTE(1)
    if (c + 2 < NC) { STAGEW(0, xA, wA) }
    __syncthreads();
  }

  // ---- epilogue: C fragments -> LDS logits tile ----
  // C layout (16x16x32): col = lane&15 (expert), row = (lane>>4)*4 + reg (token)
  {
    const int trow = wr * 16 + (l >> 4) * 4;
    const int e0 = wc * 32 + (l & 15);
#pragma unroll
    for (int r = 0; r < 4; ++r) {
      Lg[trow + r][e0]      = acc0[r];
      Lg[trow + r][e0 + 16] = acc1[r];
    }
  }
  __syncthreads();

  float* out_idx = out;
  float* out_wt  = out + NTOK * 2;
  float* out_lg  = out + NTOK * 4;

  // ---- top-4 per token (8 threads per token) ----
  {
    const int t = u >> 3;
    const int p = u & 7;
    float4 q0 = *(const float4*)(&Lg[t][p * 8]);
    float4 q1 = *(const float4*)(&Lg[t][p * 8 + 4]);

    // write logits to global (coalesced)
    float* dst = out_lg + (size_t)(tokBase + t) * NEXP + p * 8;
    *(float4*)dst = q0;
    *(float4*)(dst + 4) = q1;

    int base = p * 8;
    float a0 = q0.x, a1 = q0.y, a2 = q0.z, a3 = q0.w;
    int   ia0 = base, ia1 = base + 1, ia2 = base + 2, ia3 = base + 3;
    float b0 = q1.x, b1 = q1.y, b2 = q1.z, b3 = q1.w;
    int   ib0 = base + 4, ib1 = base + 5, ib2 = base + 6, ib3 = base + 7;
    // sort each quad desc
    CE(a0, ia0, a1, ia1) CE(a2, ia2, a3, ia3) CE(a0, ia0, a2, ia2) CE(a1, ia1, a3, ia3) CE(a1, ia1, a2, ia2)
    CE(b0, ib0, b1, ib1) CE(b2, ib2, b3, ib3) CE(b0, ib0, b2, ib2) CE(b1, ib1, b3, ib3) CE(b1, ib1, b2, ib2)
    // bitonic: top-4 of the two sorted quads
    CE(a0, ia0, b3, ib3) CE(a1, ia1, b2, ib2) CE(a2, ia2, b1, ib1) CE(a3, ia3, b0, ib0)
    CE(a0, ia0, a2, ia2) CE(a1, ia1, a3, ia3) CE(a0, ia0, a1, ia1) CE(a2, ia2, a3, ia3)

    // merge across the 8 threads of this token
#pragma unroll
    for (int m = 1; m <= 4; m <<= 1) {
      float b0s = __shfl_xor(a0, m); int ib0s = __shfl_xor(ia0, m);
      float b1s = __shfl_xor(a1, m); int ib1s = __shfl_xor(ia1, m);
      float b2s = __shfl_xor(a2, m); int ib2s = __shfl_xor(ia2, m);
      float b3s = __shfl_xor(a3, m); int ib3s = __shfl_xor(ia3, m);
      CE(a0, ia0, b3s, ib3s) CE(a1, ia1, b2s, ib2s) CE(a2, ia2, b1s, ib1s) CE(a3, ia3, b0s, ib0s)
      CE(a0, ia0, a2, ia2) CE(a1, ia1, a3, ia3) CE(a0, ia0, a1, ia1) CE(a2, ia2, a3, ia3)
    }

    if (p == 0) {
      const int tok = tokBase + t;
      bool flag = (a0 - a1 < TAU) || (a1 - a2 < TAU) || (a2 - a3 < TAU);
      if (!flag) {
        float ex = expf(a1 - a0);
        float den = 1.0f + ex;
        out_idx[tok * 2 + 0] = (float)ia0;
        out_idx[tok * 2 + 1] = (float)ia1;
        out_wt[tok * 2 + 0]  = 1.0f / den;
        out_wt[tok * 2 + 1]  = ex / den;
      } else {
        int pos = atomicAdd(&flagCount, 1);
        flagTok[pos] = t;
        flagIdx[pos] = (unsigned)ia0 | ((unsigned)ia1 << 8) | ((unsigned)ia2 << 16) | ((unsigned)ia3 << 24);
      }
    }
  }
  __syncthreads();

  // ---- fp64 fixup for near-tie tokens (rare) ----
  const int nf = flagCount;
  for (int fi = wid; fi < nf; fi += 8) {
    const int t = flagTok[fi];
    const unsigned pk = flagIdx[fi];
    const int e0 = pk & 255, e1 = (pk >> 8) & 255, e2 = (pk >> 16) & 255, e3 = (pk >> 24) & 255;
    const float* xrow = x + (size_t)(tokBase + t) * DDIM + l * 64;
    const float* w0 = wgt + (size_t)e0 * DDIM + l * 64;
    const float* w1 = wgt + (size_t)e1 * DDIM + l * 64;
    const float* w2 = wgt + (size_t)e2 * DDIM + l * 64;
    const float* w3 = wgt + (size_t)e3 * DDIM + l * 64;
    double s0 = 0.0, s1 = 0.0, s2 = 0.0, s3 = 0.0;
#pragma unroll 4
    for (int j = 0; j < 64; j += 4) {
      float4 xv = *(const float4*)(xrow + j);
      float4 av = *(const float4*)(w0 + j);
      s0 = fma((double)xv.x, (double)av.x, s0); s0 = fma((double)xv.y, (double)av.y, s0);
      s0 = fma((double)xv.z, (double)av.z, s0); s0 = fma((double)xv.w, (double)av.w, s0);
      av = *(const float4*)(w1 + j);
      s1 = fma((double)xv.x, (double)av.x, s1); s1 = fma((double)xv.y, (double)av.y, s1);
      s1 = fma((double)xv.z, (double)av.z, s1); s1 = fma((double)xv.w, (double)av.w, s1);
      av = *(const float4*)(w2 + j);
      s2 = fma((double)xv.x, (double)av.x, s2); s2 = fma((double)xv.y, (double)av.y, s2);
      s2 = fma((double)xv.z, (double)av.z, s2); s2 = fma((double)xv.w, (double)av.w, s2);
      av = *(const float4*)(w3 + j);
      s3 = fma((double)xv.x, (double)av.x, s3); s3 = fma((double)xv.y, (double)av.y, s3);
      s3 = fma((double)xv.z, (double)av.z, s3); s3 = fma((double)xv.w, (double)av.w, s3);
    }
#pragma unroll
    for (int m = 1; m < 64; m <<= 1) {
      s0 += __shfl_xor(s0, m);
      s1 += __shfl_xor(s1, m);
      s2 += __shfl_xor(s2, m);
      s3 += __shfl_xor(s3, m);
    }
    if (l == 0) {
      double v0 = s0, v1 = s1, v2 = s2, v3 = s3;
      int i0 = e0, i1 = e1, i2 = e2, i3 = e3;
      // sort 4 desc with index tiebreak
      if (betterd(v1, i1, v0, i0)) { double tv = v0; v0 = v1; v1 = tv; int ti = i0; i0 = i1; i1 = ti; }
      if (betterd(v3, i3, v2, i2)) { double tv = v2; v2 = v3; v3 = tv; int ti = i2; i2 = i3; i3 = ti; }
      if (betterd(v2, i2, v0, i0)) { double tv = v0; v0 = v2; v2 = tv; int ti = i0; i0 = i2; i2 = ti; }
      if (betterd(v3, i3, v1, i1)) { double tv = v1; v1 = v3; v3 = tv; int ti = i1; i1 = i3; i3 = ti; }
      if (betterd(v2, i2, v1, i1)) { double tv = v1; v1 = v2; v2 = tv; int ti = i1; i1 = i2; i2 = ti; }
      const int tok = tokBase + t;
      double ex = exp(v1 - v0);
      double den = 1.0 + ex;
      out_idx[tok * 2 + 0] = (float)i0;
      out_idx[tok * 2 + 1] = (float)i1;
      out_wt[tok * 2 + 0]  = (float)(1.0 / den);
      out_wt[tok * 2 + 1]  = (float)(ex / den);
    }
  }
}

extern "C" void kernel_launch(void* const* d_in, const int* in_sizes, int n_in,
                              void* d_out, int out_size, void* d_ws, size_t ws_size,
                              hipStream_t stream) {
  const float* x = (const float*)d_in[0];   // [4,4096,4096] f32
  const float* w = (const float*)d_in[1];   // [64,4096] f32
  float* out = (float*)d_out;               // 32768 idx + 32768 wt + 1048576 logits (all f32)
  dim3 grid(NTOK / TM);   // 256 blocks, 1 per CU
  dim3 block(NTHR);       // 512 threads = 8 waves
  hipLaunchKernelGGL(topk_router_mfma, grid, block, 0, stream, x, w, out);
}